// Round 5
// baseline (117.180 us; speedup 1.0000x reference)
//
#include <hip/hip_runtime.h>
#include <math.h>

// NetVLAD fp32: N=32, D=512, K=64, P=1024
// ws footprint kept at the R2-PROVEN 8.7 MB (R3's 24 MB failed => ws overflow).
// k0 : W_T[d][k] transpose.
// k1a: logits GEMM, k-split x2 (softmax deferred), full-D 8x8 lane tile,
//      writes raw logits to At[n][p][k] (k-fast => linear glds for k2a).
// k1b: + bias, softmax over k IN PLACE on At (block owns disjoint p-rows),
//      spart[n][16][k] column sums.
// k2a: V GEMM, d-split x8; per block 4 waves each accumulate 256 p of the
//      full 64k x 64d tile (8x8 lane tile), lane-keyed LDS reduction
//      (conflict-free, deterministic), then -s*c, raw V -> d_out,
//      partial ssq -> ssqp[n][k][dt].
// k2c: intra + global L2 normalization, in-place scale of d_out (R2-proven).

namespace {

constexpr int NI   = 32;
constexpr int DIMC = 512;
constexpr int KCL  = 64;
constexpr int PIXN = 1024;
constexpr float EPSF = 1e-12f;

#define AS1 __attribute__((address_space(1)))
#define AS3 __attribute__((address_space(3)))

__device__ __forceinline__ void glds16(const float* g, float* l) {
  __builtin_amdgcn_global_load_lds((const AS1 void*)g, (AS3 void*)l, 16, 0, 0);
}

// ---------------------------------------------------------------------------
__global__ __launch_bounds__(256) void k0_wt(const float* __restrict__ w,
                                             float* __restrict__ wt) {
  const int i = blockIdx.x * 256 + threadIdx.x;   // 32768
  const int d = i >> 6, k = i & 63;
  wt[i] = w[(size_t)k * DIMC + d];
}

// ---------------------------------------------------------------------------
// k1a: 256 blocks = (n, pg 0..3 [256p], kh 0..1 [32k]); 256 thr = 4 waves.
// Wave w: p-sub 64w. Lane (lk=l&3, lp=l>>2): k = kb+8lk+i, p = pb+64w+4lp+j.
// Per dd: 2 b128 (W, 8k) + 1 b128 (x, 4p) = 36 DS-cyc vs 64 VALU-cyc.
// ---------------------------------------------------------------------------
__global__ __launch_bounds__(256) void k1a_gemm(
    const float* __restrict__ x, const float* __restrict__ wt,
    float* __restrict__ At)
{
  __shared__ float xs[2][8192];   // [dd 32][p 256], 64 KB
  __shared__ float wl[2][1024];   // [dd 32][k 32],   8 KB
  const int tid = threadIdx.x;
  const int w  = __builtin_amdgcn_readfirstlane(tid >> 6);
  const int l  = tid & 63;
  const int lk = l & 3, lp = l >> 2;
  const int bid = blockIdx.x;
  const int xcd = bid & 7, rest = bid >> 3;
  const int n  = xcd + ((rest & 3) << 3);   // n -> XCD n%8
  const int pg = (rest >> 2) & 3;
  const int kh = rest >> 4;
  const int pb = pg << 8;
  const int kb = kh << 5;

  const float* xn = x + (size_t)n * DIMC * PIXN + pb;
  const float* wn = wt + kb;

  // stage chunk 0 (x: 32dd x 256p, W: 32dd x 32k) — all linear glds
#pragma unroll
  for (int s = 0; s < 8; ++s) {
    const int idx = s * 256 + tid;
    glds16(xn + (size_t)(idx >> 6) * PIXN + ((idx & 63) << 2), &xs[0][idx << 2]);
  }
  glds16(wn + (size_t)(tid >> 3) * KCL + ((tid & 7) << 2), &wl[0][tid << 2]);

  float acc[8][4];
#pragma unroll
  for (int i = 0; i < 8; ++i)
#pragma unroll
    for (int j = 0; j < 4; ++j) acc[i][j] = 0.0f;

  for (int ch = 0; ch < 16; ++ch) {   // D in chunks of 32
    const int cur = ch & 1;
    __syncthreads();                  // implicit vmcnt(0): chunk ch landed
    if (ch < 15) {                    // prefetch ch+1 (overlaps compute)
      const float* xc = xn + (size_t)((ch + 1) * 32) * PIXN;
      const float* wc = wn + (size_t)((ch + 1) * 32) * KCL;
#pragma unroll
      for (int s = 0; s < 8; ++s) {
        const int idx = s * 256 + tid;
        glds16(xc + (size_t)(idx >> 6) * PIXN + ((idx & 63) << 2),
               &xs[cur ^ 1][idx << 2]);
      }
      glds16(wc + (size_t)(tid >> 3) * KCL + ((tid & 7) << 2),
             &wl[cur ^ 1][tid << 2]);
    }
    const float* wr = &wl[cur][lk << 3];
    const float* xr = &xs[cur][(w << 6) + (lp << 2)];
#pragma unroll 4
    for (int dd = 0; dd < 32; ++dd) {
      const float4 wa = *reinterpret_cast<const float4*>(wr + (dd << 5));
      const float4 wb = *reinterpret_cast<const float4*>(wr + (dd << 5) + 4);
      const float4 xa = *reinterpret_cast<const float4*>(xr + (dd << 8));
      const float wv[8] = {wa.x, wa.y, wa.z, wa.w, wb.x, wb.y, wb.z, wb.w};
      const float xv[4] = {xa.x, xa.y, xa.z, xa.w};
#pragma unroll
      for (int i = 0; i < 8; ++i)
#pragma unroll
        for (int j = 0; j < 4; ++j)
          acc[i][j] = fmaf(wv[i], xv[j], acc[i][j]);
    }
  }

  // store raw logits to At[n][p][k]
  const size_t prow = (size_t)n * PIXN + pb + (w << 6) + (lp << 2);
#pragma unroll
  for (int j = 0; j < 4; ++j) {
    float* op = At + (prow + j) * KCL + kb + (lk << 3);
    *reinterpret_cast<float4*>(op) =
        make_float4(acc[0][j], acc[1][j], acc[2][j], acc[3][j]);
    *reinterpret_cast<float4*>(op + 4) =
        make_float4(acc[4][j], acc[5][j], acc[6][j], acc[7][j]);
  }
}

// ---------------------------------------------------------------------------
// k1b: 512 blocks = (n, ps 0..15 [64p]); 256 thr = 4 waves; lane = pixel.
// Wave v owns k 16v..16v+15 of row p. In-place softmax on At + spart.
// ---------------------------------------------------------------------------
__global__ __launch_bounds__(256) void k1b_softmax(
    float* __restrict__ At, const float* __restrict__ conv_b,
    float* __restrict__ spart)
{
  __shared__ float red[2][4][64];
  const int tid = threadIdx.x;
  const int v = __builtin_amdgcn_readfirstlane(tid >> 6);
  const int l = tid & 63;
  const int bid = blockIdx.x;
  const int xcd = bid & 7, rest = bid >> 3;
  const int n  = xcd + ((rest & 3) << 3);
  const int ps = rest >> 2;           // 0..15
  const int k0 = v << 4;

  float* base = At + ((size_t)n * PIXN + (ps << 6) + l) * KCL + k0;

  float a[16];
#pragma unroll
  for (int q = 0; q < 4; ++q) {
    const float4 t = *reinterpret_cast<const float4*>(base + (q << 2));
    const float4 b = *reinterpret_cast<const float4*>(conv_b + k0 + (q << 2));
    a[q * 4 + 0] = t.x + b.x; a[q * 4 + 1] = t.y + b.y;
    a[q * 4 + 2] = t.z + b.z; a[q * 4 + 3] = t.w + b.w;
  }

  float pmax = a[0];
#pragma unroll
  for (int kk = 1; kk < 16; ++kk) pmax = fmaxf(pmax, a[kk]);
  red[0][v][l] = pmax;
  __syncthreads();
  float m = red[0][0][l];
#pragma unroll
  for (int j = 1; j < 4; ++j) m = fmaxf(m, red[0][j][l]);
  float ps_ = 0.0f;
#pragma unroll
  for (int kk = 0; kk < 16; ++kk) { a[kk] = __expf(a[kk] - m); ps_ += a[kk]; }
  red[1][v][l] = ps_;
  __syncthreads();
  float S = red[1][0][l];
#pragma unroll
  for (int j = 1; j < 4; ++j) S += red[1][j][l];
  const float rS = 1.0f / S;
#pragma unroll
  for (int kk = 0; kk < 16; ++kk) a[kk] *= rS;

#pragma unroll
  for (int q = 0; q < 4; ++q)
    *reinterpret_cast<float4*>(base + (q << 2)) =
        make_float4(a[q * 4], a[q * 4 + 1], a[q * 4 + 2], a[q * 4 + 3]);

#pragma unroll
  for (int kk = 0; kk < 16; ++kk) {
    float sv = a[kk];
#pragma unroll
    for (int off = 32; off > 0; off >>= 1) sv += __shfl_xor(sv, off, 64);
    if (l == 0) spart[((size_t)n * 16 + ps) * KCL + k0 + kk] = sv;
  }
}

// ---------------------------------------------------------------------------
// k2a: 256 blocks = (n, dt 0..7 [64d]); 256 thr = 4 waves.
// Each wave accumulates the FULL 64k x 64d tile over its own 256 p
// (lane tile 8k x 8d: lk=l&7, ld=l>>3), then lane-keyed LDS reduction.
// A chunk [32p][64k] via linear glds (At is [p][k]); x chunk [32p][64d]
// reg-stage transposed (conflict-free: lanes write consecutive d).
// ---------------------------------------------------------------------------
__global__ __launch_bounds__(256) void k2a_vlad(
    const float* __restrict__ x, const float* __restrict__ At,
    const float* __restrict__ spart, const float* __restrict__ cent,
    float* __restrict__ out, float* __restrict__ ssqp)
{
  __shared__ float smem[8192];   // alT[b]=smem+b*2048; xT[b]=smem+4096+b*2048
  const int tid = threadIdx.x;
  const int w  = __builtin_amdgcn_readfirstlane(tid >> 6);
  const int l  = tid & 63;
  const int lk = l & 7, ld = l >> 3;
  const int bid = blockIdx.x;
  const int xcd = bid & 7, rest = bid >> 3;
  const int n  = xcd + ((rest & 3) << 3);
  const int dt = rest >> 2;           // 0..7
  const int d0 = dt << 6;

  const float* an  = At + (size_t)n * PIXN * KCL;
  const float* gxr = x + ((size_t)n * DIMC + d0 + l) * PIXN + (w << 3)
                     + ((tid >> 6) - w) * 0;   // thread row = d0 + (tid&63)
  // NOTE: staging role uses full tid: dloc = tid&63 == l, pq = tid>>6 == w.

  float4 rxa, rxb;
  // prologue: chunk 0
#pragma unroll
  for (int s = 0; s < 2; ++s) {
    const int idx = s * 256 + tid;
    glds16(an + (idx << 2), &smem[idx << 2]);
  }
  rxa = *reinterpret_cast<const float4*>(gxr);
  rxb = *reinterpret_cast<const float4*>(gxr + 4);
  {
    float* xw = &smem[4096 + (w << 9) + l];
    xw[0] = rxa.x; xw[64] = rxa.y; xw[128] = rxa.z; xw[192] = rxa.w;
    xw[256] = rxb.x; xw[320] = rxb.y; xw[384] = rxb.z; xw[448] = rxb.w;
  }
  __syncthreads();

  float acc[8][8];
#pragma unroll
  for (int i = 0; i < 8; ++i)
#pragma unroll
    for (int j = 0; j < 8; ++j) acc[i][j] = 0.0f;

  for (int pc = 0; pc < 32; ++pc) {   // P in chunks of 32; wave w does 8 p
    const int cur = pc & 1;
    if (pc < 31) {                    // prefetch chunk pc+1
#pragma unroll
      for (int s = 0; s < 2; ++s) {
        const int idx = s * 256 + tid;
        glds16(an + (size_t)(pc + 1) * 2048 + (idx << 2),
               &smem[(cur ^ 1) * 2048 + (idx << 2)]);
      }
      rxa = *reinterpret_cast<const float4*>(gxr + (pc + 1) * 32);
      rxb = *reinterpret_cast<const float4*>(gxr + (pc + 1) * 32 + 4);
    }
    const float* ar = &smem[cur * 2048 + (lk << 3)];
    const float* xr = &smem[4096 + cur * 2048 + (ld << 3)];
#pragma unroll
    for (int s = 0; s < 8; ++s) {
      const int pp = (w << 3) + s;
      const float4 a0 = *reinterpret_cast<const float4*>(ar + (pp << 6));
      const float4 a1 = *reinterpret_cast<const float4*>(ar + (pp << 6) + 4);
      const float4 x0 = *reinterpret_cast<const float4*>(xr + (pp << 6));
      const float4 x1 = *reinterpret_cast<const float4*>(xr + (pp << 6) + 4);
      const float av[8] = {a0.x, a0.y, a0.z, a0.w, a1.x, a1.y, a1.z, a1.w};
      const float xv[8] = {x0.x, x0.y, x0.z, x0.w, x1.x, x1.y, x1.z, x1.w};
#pragma unroll
      for (int i = 0; i < 8; ++i)
#pragma unroll
        for (int j = 0; j < 8; ++j)
          acc[i][j] = fmaf(av[i], xv[j], acc[i][j]);
    }
    if (pc < 31) {
      float* xw = &smem[4096 + (cur ^ 1) * 2048 + (w << 9) + l];
      xw[0] = rxa.x; xw[64] = rxa.y; xw[128] = rxa.z; xw[192] = rxa.w;
      xw[256] = rxb.x; xw[320] = rxb.y; xw[384] = rxb.z; xw[448] = rxb.w;
    }
    __syncthreads();
  }

  // lane-keyed cross-wave reduction: slot (i,jh) at (i*2+jh)*256 + l*4.
  // Reader lane l reads exactly what writer lane l wrote (same (k,d) map).
#define TSTORE(RB)                                                          \
  _Pragma("unroll") for (int i = 0; i < 8; ++i) {                           \
    *reinterpret_cast<float4*>((RB) + ((i * 2 + 0) << 8) + (l << 2)) =      \
        make_float4(acc[i][0], acc[i][1], acc[i][2], acc[i][3]);            \
    *reinterpret_cast<float4*>((RB) + ((i * 2 + 1) << 8) + (l << 2)) =      \
        make_float4(acc[i][4], acc[i][5], acc[i][6], acc[i][7]);            \
  }
#define TADD(RB)                                                            \
  _Pragma("unroll") for (int i = 0; i < 8; ++i) {                           \
    const float4 t0 = *reinterpret_cast<const float4*>(                     \
        (RB) + ((i * 2 + 0) << 8) + (l << 2));                              \
    const float4 t1 = *reinterpret_cast<const float4*>(                     \
        (RB) + ((i * 2 + 1) << 8) + (l << 2));                              \
    acc[i][0] += t0.x; acc[i][1] += t0.y; acc[i][2] += t0.z;                \
    acc[i][3] += t0.w; acc[i][4] += t1.x; acc[i][5] += t1.y;                \
    acc[i][6] += t1.z; acc[i][7] += t1.w;                                   \
  }

  if (w == 1) { TSTORE(smem) }
  if (w == 3) { TSTORE(smem + 4096) }
  __syncthreads();
  if (w == 0) { TADD(smem) }          // acc = w0+w1
  if (w == 2) { TADD(smem + 4096) }   // acc = w2+w3
  __syncthreads();
  if (w == 2) { TSTORE(smem) }
  __syncthreads();

  if (w == 0) {
    TADD(smem)                        // acc = (w0+w1)+(w2+w3), fixed order
    const float* sp = spart + (size_t)n * 16 * KCL;
#pragma unroll
    for (int i = 0; i < 8; ++i) {
      const int k = (lk << 3) + i;
      float s = 0.0f;
#pragma unroll
      for (int pt = 0; pt < 16; ++pt) s += sp[pt * KCL + k];  // fixed order
      const float* cp = cent + (size_t)k * DIMC + d0 + (ld << 3);
      const float4 c0 = *reinterpret_cast<const float4*>(cp);
      const float4 c1 = *reinterpret_cast<const float4*>(cp + 4);
      float r[8];
      r[0] = acc[i][0] - s * c0.x; r[1] = acc[i][1] - s * c0.y;
      r[2] = acc[i][2] - s * c0.z; r[3] = acc[i][3] - s * c0.w;
      r[4] = acc[i][4] - s * c1.x; r[5] = acc[i][5] - s * c1.y;
      r[6] = acc[i][6] - s * c1.z; r[7] = acc[i][7] - s * c1.w;
      float* op = out + ((size_t)n * KCL + k) * DIMC + d0 + (ld << 3);
      *reinterpret_cast<float4*>(op) = make_float4(r[0], r[1], r[2], r[3]);
      *reinterpret_cast<float4*>(op + 4) = make_float4(r[4], r[5], r[6], r[7]);
      float q = 0.0f;
#pragma unroll
      for (int j = 0; j < 8; ++j) q = fmaf(r[j], r[j], q);
      q += __shfl_xor(q, 8, 64);      // reduce over ld (l bits 3..5)
      q += __shfl_xor(q, 16, 64);
      q += __shfl_xor(q, 32, 64);
      if (ld == 0) ssqp[((size_t)n * KCL + k) * 8 + dt] = q;
    }
  }
#undef TSTORE
#undef TADD
}

// ---------------------------------------------------------------------------
// k2c: 256 blocks = (n, kc 0..7); intra + global norm, in-place (R2-proven).
// ---------------------------------------------------------------------------
__global__ __launch_bounds__(256) void k2c_norm(
    const float* __restrict__ ssqp, float* __restrict__ out)
{
  __shared__ float invs[64];
  __shared__ float gsh;
  const int tid = threadIdx.x;
  const int n  = blockIdx.x >> 3;
  const int kc = blockIdx.x & 7;
  if (tid < 64) {
    float ssq = 0.0f;
#pragma unroll
    for (int dt = 0; dt < 8; ++dt)
      ssq += ssqp[((size_t)n * KCL + tid) * 8 + dt];   // fixed order
    const float inv = 1.0f / fmaxf(sqrtf(ssq), EPSF);
    invs[tid] = inv;
    float rqv = ssq * inv * inv;
#pragma unroll
    for (int off = 32; off > 0; off >>= 1) rqv += __shfl_xor(rqv, off, 64);
    if (tid == 0) gsh = 1.0f / fmaxf(sqrtf(rqv), EPSF);
  }
  __syncthreads();
  const float sc = invs[(kc << 3) + (tid >> 5)] * gsh;
  float* o = out + ((size_t)n * KCL + (kc << 3)) * DIMC + tid * 16;
#pragma unroll
  for (int q = 0; q < 4; ++q) {
    float4 v = *reinterpret_cast<float4*>(o + (q << 2));
    v.x *= sc; v.y *= sc; v.z *= sc; v.w *= sc;
    *reinterpret_cast<float4*>(o + (q << 2)) = v;
  }
}

}  // namespace

extern "C" void kernel_launch(void* const* d_in, const int* in_sizes, int n_in,
                              void* d_out, int out_size, void* d_ws, size_t ws_size,
                              hipStream_t stream) {
  (void)in_sizes; (void)n_in; (void)out_size; (void)ws_size;
  const float* x      = (const float*)d_in[0];
  const float* cent   = (const float*)d_in[1];
  const float* conv_w = (const float*)d_in[2];
  const float* conv_b = (const float*)d_in[3];
  float* out = (float*)d_out;
  float* ws  = (float*)d_ws;

  // ws (floats): At 2097152 | wt 32768 | spart 32768 | ssqp 16384  = 8.72 MB
  // (identical footprint to the PASSING R2 run; R3's 24 MB overflowed ws).
  float* At    = ws;
  float* wt    = At + (size_t)NI * PIXN * KCL;
  float* spart = wt + 32768;
  float* ssqp  = spart + (size_t)NI * 16 * KCL;

  k0_wt      <<<128, 256, 0, stream>>>(conv_w, wt);
  k1a_gemm   <<<256, 256, 0, stream>>>(x, wt, At);
  k1b_softmax<<<512, 256, 0, stream>>>(At, conv_b, spart);
  k2a_vlad   <<<256, 256, 0, stream>>>(x, At, spart, cent, out, ssqp);
  k2c_norm   <<<256, 256, 0, stream>>>(ssqp, out);
}

// Round 7
// 88.810 us; speedup vs baseline: 1.3194x; 1.3194x over previous
//
#include <hip/hip_runtime.h>
#include <math.h>

// NetVLAD fp32: N=32, D=512, K=64, P=1024
// ws = A(8MB) + wt(128KB) + ssqp(64KB) = 8.59 MB (R2/R4-proven level).
// d_out is ONLY written by k2a/k2c (R5 crashed: plog 8MB > d_out 4MB).
// k0 : wt[d][k] transpose.
// k1a: logits GEMM + FUSED softmax. Grid 512 = (n x 16 p-tiles of 64),
//      256 thr = 4 waves; each wave accumulates the full 64k x 64p tile
//      (8x8 lane tile) over a distinct 128-d slice; lane-keyed LDS tree
//      reduces 4 partials; wave0 does softmax (in-lane + 3 shfl over lk)
//      and writes A[n][p][k].
// k2a: V GEMM. Grid 256 = (n x 8 dt of 64d), 512 thr = 8 waves (2/SIMD);
//      each wave: full 64k x 64d tile (8x8 lane) over its 128 p; s = sum_p a
//      on the fly; 3-round lane-keyed LDS tree; -s*c; raw V -> d_out;
//      partial ssq -> ssqp. Reduction scratch unions with staging (73.7KB).
// k2c: intra + global L2 norm in place (R4-proven).

namespace {

constexpr int NI   = 32;
constexpr int DIMC = 512;
constexpr int KCL  = 64;
constexpr int PIXN = 1024;
constexpr float EPSF = 1e-12f;

#define AS1 __attribute__((address_space(1)))
#define AS3 __attribute__((address_space(3)))

__device__ __forceinline__ void glds16(const float* g, float* l) {
  __builtin_amdgcn_global_load_lds((const AS1 void*)g, (AS3 void*)l, 16, 0, 0);
}

// ---------------------------------------------------------------------------
__global__ __launch_bounds__(256) void k0_wt(const float* __restrict__ w,
                                             float* __restrict__ wt) {
  const int i = blockIdx.x * 256 + threadIdx.x;   // 32768, wt[d][k]
  wt[i] = w[(size_t)(i & 63) * DIMC + (i >> 6)];
}

// ---------------------------------------------------------------------------
// k1a: 512 blocks = (n, pg 0..15 [64p]); 256 thr = 4 waves.
// Chunk = 64 d staged (x[64dd][64p], W[64dd][64k]); wave w computes
// dd in [16w, 16w+16) of each chunk -> after 8 chunks wave holds a 128-d
// partial of the full 64k x 64p tile. Lane (lk=l&7, ld=l>>3):
// k = 8lk+i, p = pb+8ld+j. Tree-reduce, then w0: bias+softmax+write A.
// ---------------------------------------------------------------------------
__global__ __launch_bounds__(256, 2) void k1a_logits(
    const float* __restrict__ x, const float* __restrict__ wt,
    const float* __restrict__ conv_b, float* __restrict__ A)
{
  __shared__ float smem[16384];       // xs[2][4096] | wl[2][4096]; scr=smem
  float* const xs0 = smem;            // [buf][dd*64 + p]
  float* const wl0 = smem + 8192;     // [buf][dd*64 + k]
  float* const scr = smem;            // 2 slots x 4096 (staging dead)

  const int tid = threadIdx.x;
  const int w  = __builtin_amdgcn_readfirstlane(tid >> 6);
  const int l  = tid & 63;
  const int lk = l & 7, ld = l >> 3;
  const int bid = blockIdx.x;
  const int xcd = bid & 7, rest = bid >> 3;   // n -> XCD n%8
  const int n  = xcd + ((rest & 3) << 3);
  const int pg = rest >> 2;                   // 0..15
  const int pb = pg << 6;

  const float* xn = x + (size_t)n * DIMC * PIXN + pb;

  // prologue: stage chunk 0 (x: 64dd x 64p, W: 64dd x 64k), linear glds
#pragma unroll
  for (int s = 0; s < 4; ++s) {
    const int i = s * 256 + tid;
    glds16(xn + (size_t)(i >> 4) * PIXN + ((i & 15) << 2), xs0 + (i << 2));
    glds16(wt + (i << 2), wl0 + (i << 2));
  }

  float acc[8][8];
#pragma unroll
  for (int i = 0; i < 8; ++i)
#pragma unroll
    for (int j = 0; j < 8; ++j) acc[i][j] = 0.0f;

  for (int ch = 0; ch < 8; ++ch) {    // 512 d in chunks of 64
    const int cur = ch & 1;
    __syncthreads();                  // chunk ch landed (vmcnt drain @ bar)
    if (ch < 7) {                     // issue prefetch ch+1 (overlaps compute)
      const float* xc = xn + (size_t)((ch + 1) * 64) * PIXN;
      const float* wc = wt + (ch + 1) * 4096;
#pragma unroll
      for (int s = 0; s < 4; ++s) {
        const int i = s * 256 + tid;
        glds16(xc + (size_t)(i >> 4) * PIXN + ((i & 15) << 2),
               xs0 + (cur ^ 1) * 4096 + (i << 2));
        glds16(wc + (i << 2), wl0 + (cur ^ 1) * 4096 + (i << 2));
      }
    }
    const float* wr = wl0 + cur * 4096 + (w << 10) + (lk << 3);  // dd16 base
    const float* xr = xs0 + cur * 4096 + (w << 10) + (ld << 3);
#pragma unroll 4
    for (int dd = 0; dd < 16; ++dd) {
      const float4 wa = *reinterpret_cast<const float4*>(wr + (dd << 6));
      const float4 wb = *reinterpret_cast<const float4*>(wr + (dd << 6) + 4);
      const float4 xa = *reinterpret_cast<const float4*>(xr + (dd << 6));
      const float4 xb = *reinterpret_cast<const float4*>(xr + (dd << 6) + 4);
      const float wv[8] = {wa.x, wa.y, wa.z, wa.w, wb.x, wb.y, wb.z, wb.w};
      const float xv[8] = {xa.x, xa.y, xa.z, xa.w, xb.x, xb.y, xb.z, xb.w};
#pragma unroll
      for (int i = 0; i < 8; ++i)
#pragma unroll
        for (int j = 0; j < 8; ++j)
          acc[i][j] = fmaf(wv[i], xv[j], acc[i][j]);
    }
  }
  __syncthreads();                    // all compute done; staging dead

  // lane-keyed tree reduction (writer lane == reader lane; fixed order)
#define TST(RB)                                                              \
  do {                                                                       \
    _Pragma("unroll") for (int i = 0; i < 8; ++i) {                          \
      *reinterpret_cast<float4*>((RB) + ((2 * i) << 8) + (l << 2)) =         \
          make_float4(acc[i][0], acc[i][1], acc[i][2], acc[i][3]);           \
      *reinterpret_cast<float4*>((RB) + ((2 * i + 1) << 8) + (l << 2)) =     \
          make_float4(acc[i][4], acc[i][5], acc[i][6], acc[i][7]);           \
    }                                                                        \
  } while (0)
#define TADD(RB)                                                             \
  do {                                                                       \
    _Pragma("unroll") for (int i = 0; i < 8; ++i) {                          \
      const float4 t0 = *reinterpret_cast<const float4*>(                    \
          (RB) + ((2 * i) << 8) + (l << 2));                                 \
      const float4 t1 = *reinterpret_cast<const float4*>(                    \
          (RB) + ((2 * i + 1) << 8) + (l << 2));                             \
      acc[i][0] += t0.x; acc[i][1] += t0.y; acc[i][2] += t0.z;               \
      acc[i][3] += t0.w; acc[i][4] += t1.x; acc[i][5] += t1.y;               \
      acc[i][6] += t1.z; acc[i][7] += t1.w;                                  \
    }                                                                        \
  } while (0)

  if (w == 1) TST(scr);
  if (w == 3) TST(scr + 4096);
  __syncthreads();
  if (w == 0) TADD(scr);              // w0 = w0+w1
  if (w == 2) TADD(scr + 4096);       // w2 = w2+w3
  __syncthreads();
  if (w == 2) TST(scr);
  __syncthreads();

  if (w == 0) {
    TADD(scr);                        // full logits (fixed tree order)
    // bias
    const float4 b0 = *reinterpret_cast<const float4*>(conv_b + (lk << 3));
    const float4 b1 = *reinterpret_cast<const float4*>(conv_b + (lk << 3) + 4);
    const float bv[8] = {b0.x, b0.y, b0.z, b0.w, b1.x, b1.y, b1.z, b1.w};
#pragma unroll
    for (int i = 0; i < 8; ++i)
#pragma unroll
      for (int j = 0; j < 8; ++j) acc[i][j] += bv[i];
    // softmax over k (= 8 regs x 8 lk-lanes) per p-column j
    float m[8], S[8];
#pragma unroll
    for (int j = 0; j < 8; ++j) {
      m[j] = acc[0][j];
#pragma unroll
      for (int i = 1; i < 8; ++i) m[j] = fmaxf(m[j], acc[i][j]);
      m[j] = fmaxf(m[j], __shfl_xor(m[j], 1, 64));
      m[j] = fmaxf(m[j], __shfl_xor(m[j], 2, 64));
      m[j] = fmaxf(m[j], __shfl_xor(m[j], 4, 64));
      S[j] = 0.0f;
#pragma unroll
      for (int i = 0; i < 8; ++i) {
        acc[i][j] = __expf(acc[i][j] - m[j]);
        S[j] += acc[i][j];
      }
      S[j] += __shfl_xor(S[j], 1, 64);
      S[j] += __shfl_xor(S[j], 2, 64);
      S[j] += __shfl_xor(S[j], 4, 64);
      S[j] = 1.0f / S[j];
    }
    // write A[n][p][k], p = pb + 8ld + j, k = 8lk..8lk+8
#pragma unroll
    for (int j = 0; j < 8; ++j) {
      float* op = A + ((size_t)n * PIXN + pb + (ld << 3) + j) * KCL + (lk << 3);
      *reinterpret_cast<float4*>(op) =
          make_float4(acc[0][j] * S[j], acc[1][j] * S[j],
                      acc[2][j] * S[j], acc[3][j] * S[j]);
      *reinterpret_cast<float4*>(op + 4) =
          make_float4(acc[4][j] * S[j], acc[5][j] * S[j],
                      acc[6][j] * S[j], acc[7][j] * S[j]);
    }
  }
#undef TST
#undef TADD
}

// ---------------------------------------------------------------------------
// k2a: 256 blocks = (n, dt 0..7 [64d]); 512 thr = 8 waves (2/SIMD).
// Wave w: full 64k x 64d tile (lane 8k x 8d) over its 128 p (8 p per 64p
// chunk x 16 chunks). s = sum_p a on the fly. 3-round lane-keyed tree.
// Scratch (4 x 4608) unions with staging -> 73.7 KB LDS.
// ---------------------------------------------------------------------------
__global__ __launch_bounds__(512, 2) void k2a_vlad(
    const float* __restrict__ x, const float* __restrict__ A,
    const float* __restrict__ cent, float* __restrict__ out,
    float* __restrict__ ssqp)
{
  __shared__ float smem[18432];   // aL[2][4096] | xL[2][4096]; scr=smem (union)
  float* const aL0 = smem;
  float* const xL0 = smem + 8192;
  float* const scr = smem;

  const int tid = threadIdx.x;
  const int w  = __builtin_amdgcn_readfirstlane(tid >> 6);
  const int l  = tid & 63;
  const int lk = l & 7, ld = l >> 3;
  const int bid = blockIdx.x;
  const int xcd = bid & 7, rest = bid >> 3;
  const int n  = xcd + ((rest & 3) << 3);
  const int dt = rest >> 2;
  const int d0 = dt << 6;

  const float* an = A + (size_t)n * PIXN * KCL;
  // x staging roles: dl = tid&63 (d-row), pq = tid>>6 (8 p each)
  const int dl = tid & 63, pq = tid >> 6;
  const float* xg = x + ((size_t)n * DIMC + d0 + dl) * PIXN + (pq << 3);

  // prologue: chunk 0
  glds16(an + (tid << 2), aL0 + (tid << 2));
  glds16(an + ((tid + 512) << 2), aL0 + ((tid + 512) << 2));
  float4 rx0 = *reinterpret_cast<const float4*>(xg);
  float4 rx1 = *reinterpret_cast<const float4*>(xg + 4);
  {
    float* xw = xL0 + (pq << 9) + dl;   // [p][d], p = 8pq..8pq+7
    xw[0]   = rx0.x; xw[64]  = rx0.y; xw[128] = rx0.z; xw[192] = rx0.w;
    xw[256] = rx1.x; xw[320] = rx1.y; xw[384] = rx1.z; xw[448] = rx1.w;
  }
  __syncthreads();

  float acc[8][8], sacc[8];
#pragma unroll
  for (int i = 0; i < 8; ++i) {
    sacc[i] = 0.0f;
#pragma unroll
    for (int j = 0; j < 8; ++j) acc[i][j] = 0.0f;
  }

  for (int ch = 0; ch < 16; ++ch) {   // P in chunks of 64; wave does 8 p
    const int cur = ch & 1;
    const float* aLc = aL0 + cur * 4096;
    const float* xLc = xL0 + cur * 4096;
    if (ch < 15) {                    // prefetch ch+1
      const float* an2 = an + (size_t)(ch + 1) * 4096;
      glds16(an2 + (tid << 2), aL0 + (cur ^ 1) * 4096 + (tid << 2));
      glds16(an2 + ((tid + 512) << 2),
             aL0 + (cur ^ 1) * 4096 + ((tid + 512) << 2));
      rx0 = *reinterpret_cast<const float4*>(xg + (ch + 1) * 64);
      rx1 = *reinterpret_cast<const float4*>(xg + (ch + 1) * 64 + 4);
    }
#pragma unroll
    for (int st = 0; st < 8; ++st) {
      const int p = (w << 3) + st;
      const float4 a0 = *reinterpret_cast<const float4*>(aLc + (p << 6) + (lk << 3));
      const float4 a1 = *reinterpret_cast<const float4*>(aLc + (p << 6) + (lk << 3) + 4);
      const float4 x0 = *reinterpret_cast<const float4*>(xLc + (p << 6) + (ld << 3));
      const float4 x1 = *reinterpret_cast<const float4*>(xLc + (p << 6) + (ld << 3) + 4);
      const float av[8] = {a0.x, a0.y, a0.z, a0.w, a1.x, a1.y, a1.z, a1.w};
      const float xv[8] = {x0.x, x0.y, x0.z, x0.w, x1.x, x1.y, x1.z, x1.w};
#pragma unroll
      for (int i = 0; i < 8; ++i) {
        sacc[i] += av[i];
#pragma unroll
        for (int j = 0; j < 8; ++j)
          acc[i][j] = fmaf(av[i], xv[j], acc[i][j]);
      }
    }
    if (ch < 15) {
      float* xw = xL0 + (cur ^ 1) * 4096 + (pq << 9) + dl;
      xw[0]   = rx0.x; xw[64]  = rx0.y; xw[128] = rx0.z; xw[192] = rx0.w;
      xw[256] = rx1.x; xw[320] = rx1.y; xw[384] = rx1.z; xw[448] = rx1.w;
    }
    __syncthreads();
  }

  // 3-round lane-keyed reduction: 18 quads/lane (16 acc + 2 sacc)
#define TST(RB)                                                              \
  do {                                                                       \
    _Pragma("unroll") for (int i = 0; i < 8; ++i) {                          \
      *reinterpret_cast<float4*>((RB) + ((2 * i) << 8) + (l << 2)) =         \
          make_float4(acc[i][0], acc[i][1], acc[i][2], acc[i][3]);           \
      *reinterpret_cast<float4*>((RB) + ((2 * i + 1) << 8) + (l << 2)) =     \
          make_float4(acc[i][4], acc[i][5], acc[i][6], acc[i][7]);           \
    }                                                                        \
    *reinterpret_cast<float4*>((RB) + (16 << 8) + (l << 2)) =                \
        make_float4(sacc[0], sacc[1], sacc[2], sacc[3]);                     \
    *reinterpret_cast<float4*>((RB) + (17 << 8) + (l << 2)) =                \
        make_float4(sacc[4], sacc[5], sacc[6], sacc[7]);                     \
  } while (0)
#define TADD(RB)                                                             \
  do {                                                                       \
    _Pragma("unroll") for (int i = 0; i < 8; ++i) {                          \
      const float4 t0 = *reinterpret_cast<const float4*>(                    \
          (RB) + ((2 * i) << 8) + (l << 2));                                 \
      const float4 t1 = *reinterpret_cast<const float4*>(                    \
          (RB) + ((2 * i + 1) << 8) + (l << 2));                             \
      acc[i][0] += t0.x; acc[i][1] += t0.y; acc[i][2] += t0.z;               \
      acc[i][3] += t0.w; acc[i][4] += t1.x; acc[i][5] += t1.y;               \
      acc[i][6] += t1.z; acc[i][7] += t1.w;                                  \
    }                                                                        \
    const float4 s0 = *reinterpret_cast<const float4*>(                      \
        (RB) + (16 << 8) + (l << 2));                                        \
    const float4 s1 = *reinterpret_cast<const float4*>(                      \
        (RB) + (17 << 8) + (l << 2));                                        \
    sacc[0] += s0.x; sacc[1] += s0.y; sacc[2] += s0.z; sacc[3] += s0.w;      \
    sacc[4] += s1.x; sacc[5] += s1.y; sacc[6] += s1.z; sacc[7] += s1.w;      \
  } while (0)

  if (w >= 4) TST(scr + (w - 4) * 4608);
  __syncthreads();
  if (w < 4) TADD(scr + w * 4608);
  __syncthreads();
  if (w == 2) TST(scr);
  if (w == 3) TST(scr + 4608);
  __syncthreads();
  if (w < 2) TADD(scr + w * 4608);
  __syncthreads();
  if (w == 1) TST(scr);
  __syncthreads();

  if (w == 0) {
    TADD(scr);   // final, deterministic fixed tree
#pragma unroll
    for (int i = 0; i < 8; ++i) {
      const int k = (lk << 3) + i;
      const float s = sacc[i];
      const float* cp = cent + (size_t)k * DIMC + d0 + (ld << 3);
      const float4 c0 = *reinterpret_cast<const float4*>(cp);
      const float4 c1 = *reinterpret_cast<const float4*>(cp + 4);
      float r[8];
      r[0] = acc[i][0] - s * c0.x; r[1] = acc[i][1] - s * c0.y;
      r[2] = acc[i][2] - s * c0.z; r[3] = acc[i][3] - s * c0.w;
      r[4] = acc[i][4] - s * c1.x; r[5] = acc[i][5] - s * c1.y;
      r[6] = acc[i][6] - s * c1.z; r[7] = acc[i][7] - s * c1.w;
      float* op = out + ((size_t)n * KCL + k) * DIMC + d0 + (ld << 3);
      *reinterpret_cast<float4*>(op)     = make_float4(r[0], r[1], r[2], r[3]);
      *reinterpret_cast<float4*>(op + 4) = make_float4(r[4], r[5], r[6], r[7]);
      float q = 0.0f;
#pragma unroll
      for (int j = 0; j < 8; ++j) q = fmaf(r[j], r[j], q);
      q += __shfl_xor(q, 8, 64);    // reduce over ld (bits 3..5)
      q += __shfl_xor(q, 16, 64);
      q += __shfl_xor(q, 32, 64);
      if (ld == 0) ssqp[((size_t)n * KCL + k) * 8 + dt] = q;
    }
  }
#undef TST
#undef TADD
}

// ---------------------------------------------------------------------------
// k2c: 256 blocks = (n, kc 0..7); intra + global norm in place (R4-proven).
// ---------------------------------------------------------------------------
__global__ __launch_bounds__(256) void k2c_norm(
    const float* __restrict__ ssqp, float* __restrict__ out)
{
  __shared__ float invs[64];
  __shared__ float gsh;
  const int tid = threadIdx.x;
  const int n  = blockIdx.x >> 3;
  const int kc = blockIdx.x & 7;
  if (tid < 64) {
    float ssq = 0.0f;
#pragma unroll
    for (int dt = 0; dt < 8; ++dt)
      ssq += ssqp[((size_t)n * KCL + tid) * 8 + dt];   // fixed order
    const float inv = 1.0f / fmaxf(sqrtf(ssq), EPSF);
    invs[tid] = inv;
    float rqv = ssq * inv * inv;
#pragma unroll
    for (int off = 32; off > 0; off >>= 1) rqv += __shfl_xor(rqv, off, 64);
    if (tid == 0) gsh = 1.0f / fmaxf(sqrtf(rqv), EPSF);
  }
  __syncthreads();
  const float sc = invs[(kc << 3) + (tid >> 5)] * gsh;
  float* o = out + ((size_t)n * KCL + (kc << 3)) * DIMC + tid * 16;
#pragma unroll
  for (int q = 0; q < 4; ++q) {
    float4 v = *reinterpret_cast<float4*>(o + (q << 2));
    v.x *= sc; v.y *= sc; v.z *= sc; v.w *= sc;
    *reinterpret_cast<float4*>(o + (q << 2)) = v;
  }
}

}  // namespace

extern "C" void kernel_launch(void* const* d_in, const int* in_sizes, int n_in,
                              void* d_out, int out_size, void* d_ws, size_t ws_size,
                              hipStream_t stream) {
  (void)in_sizes; (void)n_in; (void)out_size; (void)ws_size;
  const float* x      = (const float*)d_in[0];
  const float* cent   = (const float*)d_in[1];
  const float* conv_w = (const float*)d_in[2];
  const float* conv_b = (const float*)d_in[3];
  float* out = (float*)d_out;
  float* ws  = (float*)d_ws;

  // ws (floats): A 2097152 | wt 32768 | ssqp 16384  = 8.59 MB (proven-safe)
  float* A    = ws;
  float* wt   = A + (size_t)NI * PIXN * KCL;
  float* ssqp = wt + 32768;

  k0_wt     <<<128, 256, 0, stream>>>(conv_w, wt);
  k1a_logits<<<512, 256, 0, stream>>>(x, wt, conv_b, A);
  k2a_vlad  <<<256, 512, 0, stream>>>(x, A, cent, out, ssqp);
  k2c_norm  <<<256, 256, 0, stream>>>(ssqp, out);
}

// Round 8
// 88.202 us; speedup vs baseline: 1.3285x; 1.0069x over previous
//
#include <hip/hip_runtime.h>
#include <math.h>

// NetVLAD fp32: N=32, D=512, K=64, P=1024
// ws = A(8MB) + wt(128KB) + ssqp(64KB) = 8.59 MB (proven-safe level).
// k0 : wt[d][k] transpose.
// k1a: logits GEMM + FUSED softmax (R7-proven, unchanged).
// k2a: V GEMM. R7 structure, but x-staging fixed: COALESCED global reads
//      (thread = one d-row, 8 consecutive p = 32 B contiguous; wave = 8 rows
//      x 256 B) + 8-way-conflicted b32 LDS writes ([p][64] layout forces it;
//      write-side conflicts cost once per datum vs 8x-reused conflict-free
//      b128 reads -- beats R7's 64-scattered-lines-per-wave global pattern).
// k2c: intra + global L2 norm in place (proven).

namespace {

constexpr int NI   = 32;
constexpr int DIMC = 512;
constexpr int KCL  = 64;
constexpr int PIXN = 1024;
constexpr float EPSF = 1e-12f;

#define AS1 __attribute__((address_space(1)))
#define AS3 __attribute__((address_space(3)))

__device__ __forceinline__ void glds16(const float* g, float* l) {
  __builtin_amdgcn_global_load_lds((const AS1 void*)g, (AS3 void*)l, 16, 0, 0);
}

// ---------------------------------------------------------------------------
__global__ __launch_bounds__(256) void k0_wt(const float* __restrict__ w,
                                             float* __restrict__ wt) {
  const int i = blockIdx.x * 256 + threadIdx.x;   // 32768, wt[d][k]
  wt[i] = w[(size_t)(i & 63) * DIMC + (i >> 6)];
}

// ---------------------------------------------------------------------------
// k1a: 512 blocks = (n, pg 0..15 [64p]); 256 thr = 4 waves. (R7-proven)
// ---------------------------------------------------------------------------
__global__ __launch_bounds__(256, 2) void k1a_logits(
    const float* __restrict__ x, const float* __restrict__ wt,
    const float* __restrict__ conv_b, float* __restrict__ A)
{
  __shared__ float smem[16384];       // xs[2][4096] | wl[2][4096]; scr=smem
  float* const xs0 = smem;            // [buf][dd*64 + p]
  float* const wl0 = smem + 8192;     // [buf][dd*64 + k]
  float* const scr = smem;            // 2 slots x 4096 (staging dead)

  const int tid = threadIdx.x;
  const int w  = __builtin_amdgcn_readfirstlane(tid >> 6);
  const int l  = tid & 63;
  const int lk = l & 7, ld = l >> 3;
  const int bid = blockIdx.x;
  const int xcd = bid & 7, rest = bid >> 3;   // n -> XCD n%8
  const int n  = xcd + ((rest & 3) << 3);
  const int pg = rest >> 2;                   // 0..15
  const int pb = pg << 6;

  const float* xn = x + (size_t)n * DIMC * PIXN + pb;

#pragma unroll
  for (int s = 0; s < 4; ++s) {
    const int i = s * 256 + tid;
    glds16(xn + (size_t)(i >> 4) * PIXN + ((i & 15) << 2), xs0 + (i << 2));
    glds16(wt + (i << 2), wl0 + (i << 2));
  }

  float acc[8][8];
#pragma unroll
  for (int i = 0; i < 8; ++i)
#pragma unroll
    for (int j = 0; j < 8; ++j) acc[i][j] = 0.0f;

  for (int ch = 0; ch < 8; ++ch) {    // 512 d in chunks of 64
    const int cur = ch & 1;
    __syncthreads();
    if (ch < 7) {
      const float* xc = xn + (size_t)((ch + 1) * 64) * PIXN;
      const float* wc = wt + (ch + 1) * 4096;
#pragma unroll
      for (int s = 0; s < 4; ++s) {
        const int i = s * 256 + tid;
        glds16(xc + (size_t)(i >> 4) * PIXN + ((i & 15) << 2),
               xs0 + (cur ^ 1) * 4096 + (i << 2));
        glds16(wc + (i << 2), wl0 + (cur ^ 1) * 4096 + (i << 2));
      }
    }
    const float* wr = wl0 + cur * 4096 + (w << 10) + (lk << 3);
    const float* xr = xs0 + cur * 4096 + (w << 10) + (ld << 3);
#pragma unroll 4
    for (int dd = 0; dd < 16; ++dd) {
      const float4 wa = *reinterpret_cast<const float4*>(wr + (dd << 6));
      const float4 wb = *reinterpret_cast<const float4*>(wr + (dd << 6) + 4);
      const float4 xa = *reinterpret_cast<const float4*>(xr + (dd << 6));
      const float4 xb = *reinterpret_cast<const float4*>(xr + (dd << 6) + 4);
      const float wv[8] = {wa.x, wa.y, wa.z, wa.w, wb.x, wb.y, wb.z, wb.w};
      const float xv[8] = {xa.x, xa.y, xa.z, xa.w, xb.x, xb.y, xb.z, xb.w};
#pragma unroll
      for (int i = 0; i < 8; ++i)
#pragma unroll
        for (int j = 0; j < 8; ++j)
          acc[i][j] = fmaf(wv[i], xv[j], acc[i][j]);
    }
  }
  __syncthreads();

#define TST(RB)                                                              \
  do {                                                                       \
    _Pragma("unroll") for (int i = 0; i < 8; ++i) {                          \
      *reinterpret_cast<float4*>((RB) + ((2 * i) << 8) + (l << 2)) =         \
          make_float4(acc[i][0], acc[i][1], acc[i][2], acc[i][3]);           \
      *reinterpret_cast<float4*>((RB) + ((2 * i + 1) << 8) + (l << 2)) =     \
          make_float4(acc[i][4], acc[i][5], acc[i][6], acc[i][7]);           \
    }                                                                        \
  } while (0)
#define TADD(RB)                                                             \
  do {                                                                       \
    _Pragma("unroll") for (int i = 0; i < 8; ++i) {                          \
      const float4 t0 = *reinterpret_cast<const float4*>(                    \
          (RB) + ((2 * i) << 8) + (l << 2));                                 \
      const float4 t1 = *reinterpret_cast<const float4*>(                    \
          (RB) + ((2 * i + 1) << 8) + (l << 2));                             \
      acc[i][0] += t0.x; acc[i][1] += t0.y; acc[i][2] += t0.z;               \
      acc[i][3] += t0.w; acc[i][4] += t1.x; acc[i][5] += t1.y;               \
      acc[i][6] += t1.z; acc[i][7] += t1.w;                                  \
    }                                                                        \
  } while (0)

  if (w == 1) TST(scr);
  if (w == 3) TST(scr + 4096);
  __syncthreads();
  if (w == 0) TADD(scr);
  if (w == 2) TADD(scr + 4096);
  __syncthreads();
  if (w == 2) TST(scr);
  __syncthreads();

  if (w == 0) {
    TADD(scr);
    const float4 b0 = *reinterpret_cast<const float4*>(conv_b + (lk << 3));
    const float4 b1 = *reinterpret_cast<const float4*>(conv_b + (lk << 3) + 4);
    const float bv[8] = {b0.x, b0.y, b0.z, b0.w, b1.x, b1.y, b1.z, b1.w};
#pragma unroll
    for (int i = 0; i < 8; ++i)
#pragma unroll
      for (int j = 0; j < 8; ++j) acc[i][j] += bv[i];
    float m[8], S[8];
#pragma unroll
    for (int j = 0; j < 8; ++j) {
      m[j] = acc[0][j];
#pragma unroll
      for (int i = 1; i < 8; ++i) m[j] = fmaxf(m[j], acc[i][j]);
      m[j] = fmaxf(m[j], __shfl_xor(m[j], 1, 64));
      m[j] = fmaxf(m[j], __shfl_xor(m[j], 2, 64));
      m[j] = fmaxf(m[j], __shfl_xor(m[j], 4, 64));
      S[j] = 0.0f;
#pragma unroll
      for (int i = 0; i < 8; ++i) {
        acc[i][j] = __expf(acc[i][j] - m[j]);
        S[j] += acc[i][j];
      }
      S[j] += __shfl_xor(S[j], 1, 64);
      S[j] += __shfl_xor(S[j], 2, 64);
      S[j] += __shfl_xor(S[j], 4, 64);
      S[j] = 1.0f / S[j];
    }
#pragma unroll
    for (int j = 0; j < 8; ++j) {
      float* op = A + ((size_t)n * PIXN + pb + (ld << 3) + j) * KCL + (lk << 3);
      *reinterpret_cast<float4*>(op) =
          make_float4(acc[0][j] * S[j], acc[1][j] * S[j],
                      acc[2][j] * S[j], acc[3][j] * S[j]);
      *reinterpret_cast<float4*>(op + 4) =
          make_float4(acc[4][j] * S[j], acc[5][j] * S[j],
                      acc[6][j] * S[j], acc[7][j] * S[j]);
    }
  }
#undef TST
#undef TADD
}

// ---------------------------------------------------------------------------
// k2a: 256 blocks = (n, dt 0..7 [64d]); 512 thr = 8 waves (2/SIMD).
// Wave w: full 64k x 64d tile (lane 8k x 8d) over its 128 p. R7 structure;
// NEW x-staging: thread t = d-row (t>>3), 8 consecutive p at (t&7)*8 ->
// 32 B contiguous global reads (8 rows x 256 B per wave, coalesced);
// LDS writes 8 b32 scattered into [p][64] (8-way bank conflict, accepted).
// ---------------------------------------------------------------------------
__global__ __launch_bounds__(512, 2) void k2a_vlad(
    const float* __restrict__ x, const float* __restrict__ A,
    const float* __restrict__ cent, float* __restrict__ out,
    float* __restrict__ ssqp)
{
  __shared__ float smem[18432];   // aL[2][4096] | xL[2][4096]; scr=smem (union)
  float* const aL0 = smem;
  float* const xL0 = smem + 8192;
  float* const scr = smem;

  const int tid = threadIdx.x;
  const int w  = __builtin_amdgcn_readfirstlane(tid >> 6);
  const int l  = tid & 63;
  const int lk = l & 7, ld = l >> 3;
  const int bid = blockIdx.x;
  const int xcd = bid & 7, rest = bid >> 3;
  const int n  = xcd + ((rest & 3) << 3);
  const int dt = rest >> 2;
  const int d0 = dt << 6;

  const float* an = A + (size_t)n * PIXN * KCL;
  // x staging roles: srow = tid>>3 (d-row 0..63), sp0 = (tid&7)*8 (8 consec p)
  const int srow = tid >> 3;
  const int sp0 = (tid & 7) << 3;
  const float* gx = x + ((size_t)n * DIMC + d0 + srow) * PIXN + sp0;

  // prologue: chunk 0
  glds16(an + (tid << 2), aL0 + (tid << 2));
  glds16(an + ((tid + 512) << 2), aL0 + ((tid + 512) << 2));
  float4 rx0 = *reinterpret_cast<const float4*>(gx);
  float4 rx1 = *reinterpret_cast<const float4*>(gx + 4);
  {
    float* xw = xL0 + (sp0 << 6) + srow;   // [p][64]
    xw[0]     = rx0.x; xw[64]      = rx0.y; xw[128]     = rx0.z; xw[192] = rx0.w;
    xw[256]   = rx1.x; xw[320]     = rx1.y; xw[384]     = rx1.z; xw[448] = rx1.w;
  }
  __syncthreads();

  float acc[8][8], sacc[8];
#pragma unroll
  for (int i = 0; i < 8; ++i) {
    sacc[i] = 0.0f;
#pragma unroll
    for (int j = 0; j < 8; ++j) acc[i][j] = 0.0f;
  }

  for (int ch = 0; ch < 16; ++ch) {   // P in chunks of 64; wave does 8 p
    const int cur = ch & 1;
    const float* aLc = aL0 + cur * 4096;
    const float* xLc = xL0 + cur * 4096;
    if (ch < 15) {                    // prefetch ch+1 (coalesced)
      const float* an2 = an + (size_t)(ch + 1) * 4096;
      glds16(an2 + (tid << 2), aL0 + (cur ^ 1) * 4096 + (tid << 2));
      glds16(an2 + ((tid + 512) << 2),
             aL0 + (cur ^ 1) * 4096 + ((tid + 512) << 2));
      rx0 = *reinterpret_cast<const float4*>(gx + (ch + 1) * 64);
      rx1 = *reinterpret_cast<const float4*>(gx + (ch + 1) * 64 + 4);
    }
#pragma unroll
    for (int st = 0; st < 8; ++st) {
      const int p = (w << 3) + st;
      const float4 a0 = *reinterpret_cast<const float4*>(aLc + (p << 6) + (lk << 3));
      const float4 a1 = *reinterpret_cast<const float4*>(aLc + (p << 6) + (lk << 3) + 4);
      const float4 x0 = *reinterpret_cast<const float4*>(xLc + (p << 6) + (ld << 3));
      const float4 x1 = *reinterpret_cast<const float4*>(xLc + (p << 6) + (ld << 3) + 4);
      const float av[8] = {a0.x, a0.y, a0.z, a0.w, a1.x, a1.y, a1.z, a1.w};
      const float xv[8] = {x0.x, x0.y, x0.z, x0.w, x1.x, x1.y, x1.z, x1.w};
#pragma unroll
      for (int i = 0; i < 8; ++i) {
        sacc[i] += av[i];
#pragma unroll
        for (int j = 0; j < 8; ++j)
          acc[i][j] = fmaf(av[i], xv[j], acc[i][j]);
      }
    }
    if (ch < 15) {
      float* xw = xL0 + (cur ^ 1) * 4096 + (sp0 << 6) + srow;
      xw[0]   = rx0.x; xw[64]  = rx0.y; xw[128] = rx0.z; xw[192] = rx0.w;
      xw[256] = rx1.x; xw[320] = rx1.y; xw[384] = rx1.z; xw[448] = rx1.w;
    }
    __syncthreads();
  }

  // 3-round lane-keyed reduction: 18 quads/lane (16 acc + 2 sacc)
#define TST(RB)                                                              \
  do {                                                                       \
    _Pragma("unroll") for (int i = 0; i < 8; ++i) {                          \
      *reinterpret_cast<float4*>((RB) + ((2 * i) << 8) + (l << 2)) =         \
          make_float4(acc[i][0], acc[i][1], acc[i][2], acc[i][3]);           \
      *reinterpret_cast<float4*>((RB) + ((2 * i + 1) << 8) + (l << 2)) =     \
          make_float4(acc[i][4], acc[i][5], acc[i][6], acc[i][7]);           \
    }                                                                        \
    *reinterpret_cast<float4*>((RB) + (16 << 8) + (l << 2)) =                \
        make_float4(sacc[0], sacc[1], sacc[2], sacc[3]);                     \
    *reinterpret_cast<float4*>((RB) + (17 << 8) + (l << 2)) =                \
        make_float4(sacc[4], sacc[5], sacc[6], sacc[7]);                     \
  } while (0)
#define TADD(RB)                                                             \
  do {                                                                       \
    _Pragma("unroll") for (int i = 0; i < 8; ++i) {                          \
      const float4 t0 = *reinterpret_cast<const float4*>(                    \
          (RB) + ((2 * i) << 8) + (l << 2));                                 \
      const float4 t1 = *reinterpret_cast<const float4*>(                    \
          (RB) + ((2 * i + 1) << 8) + (l << 2));                             \
      acc[i][0] += t0.x; acc[i][1] += t0.y; acc[i][2] += t0.z;               \
      acc[i][3] += t0.w; acc[i][4] += t1.x; acc[i][5] += t1.y;               \
      acc[i][6] += t1.z; acc[i][7] += t1.w;                                  \
    }                                                                        \
    const float4 s0 = *reinterpret_cast<const float4*>(                      \
        (RB) + (16 << 8) + (l << 2));                                        \
    const float4 s1 = *reinterpret_cast<const float4*>(                      \
        (RB) + (17 << 8) + (l << 2));                                        \
    sacc[0] += s0.x; sacc[1] += s0.y; sacc[2] += s0.z; sacc[3] += s0.w;      \
    sacc[4] += s1.x; sacc[5] += s1.y; sacc[6] += s1.z; sacc[7] += s1.w;      \
  } while (0)

  if (w >= 4) TST(scr + (w - 4) * 4608);
  __syncthreads();
  if (w < 4) TADD(scr + w * 4608);
  __syncthreads();
  if (w == 2) TST(scr);
  if (w == 3) TST(scr + 4608);
  __syncthreads();
  if (w < 2) TADD(scr + w * 4608);
  __syncthreads();
  if (w == 1) TST(scr);
  __syncthreads();

  if (w == 0) {
    TADD(scr);   // final, deterministic fixed tree
#pragma unroll
    for (int i = 0; i < 8; ++i) {
      const int k = (lk << 3) + i;
      const float s = sacc[i];
      const float* cp = cent + (size_t)k * DIMC + d0 + (ld << 3);
      const float4 c0 = *reinterpret_cast<const float4*>(cp);
      const float4 c1 = *reinterpret_cast<const float4*>(cp + 4);
      float r[8];
      r[0] = acc[i][0] - s * c0.x; r[1] = acc[i][1] - s * c0.y;
      r[2] = acc[i][2] - s * c0.z; r[3] = acc[i][3] - s * c0.w;
      r[4] = acc[i][4] - s * c1.x; r[5] = acc[i][5] - s * c1.y;
      r[6] = acc[i][6] - s * c1.z; r[7] = acc[i][7] - s * c1.w;
      float* op = out + ((size_t)n * KCL + k) * DIMC + d0 + (ld << 3);
      *reinterpret_cast<float4*>(op)     = make_float4(r[0], r[1], r[2], r[3]);
      *reinterpret_cast<float4*>(op + 4) = make_float4(r[4], r[5], r[6], r[7]);
      float q = 0.0f;
#pragma unroll
      for (int j = 0; j < 8; ++j) q = fmaf(r[j], r[j], q);
      q += __shfl_xor(q, 8, 64);
      q += __shfl_xor(q, 16, 64);
      q += __shfl_xor(q, 32, 64);
      if (ld == 0) ssqp[((size_t)n * KCL + k) * 8 + dt] = q;
    }
  }
#undef TST
#undef TADD
}

// ---------------------------------------------------------------------------
// k2c: 256 blocks = (n, kc 0..7); intra + global norm in place (proven).
// ---------------------------------------------------------------------------
__global__ __launch_bounds__(256) void k2c_norm(
    const float* __restrict__ ssqp, float* __restrict__ out)
{
  __shared__ float invs[64];
  __shared__ float gsh;
  const int tid = threadIdx.x;
  const int n  = blockIdx.x >> 3;
  const int kc = blockIdx.x & 7;
  if (tid < 64) {
    float ssq = 0.0f;
#pragma unroll
    for (int dt = 0; dt < 8; ++dt)
      ssq += ssqp[((size_t)n * KCL + tid) * 8 + dt];   // fixed order
    const float inv = 1.0f / fmaxf(sqrtf(ssq), EPSF);
    invs[tid] = inv;
    float rqv = ssq * inv * inv;
#pragma unroll
    for (int off = 32; off > 0; off >>= 1) rqv += __shfl_xor(rqv, off, 64);
    if (tid == 0) gsh = 1.0f / fmaxf(sqrtf(rqv), EPSF);
  }
  __syncthreads();
  const float sc = invs[(kc << 3) + (tid >> 5)] * gsh;
  float* o = out + ((size_t)n * KCL + (kc << 3)) * DIMC + tid * 16;
#pragma unroll
  for (int q = 0; q < 4; ++q) {
    float4 v = *reinterpret_cast<float4*>(o + (q << 2));
    v.x *= sc; v.y *= sc; v.z *= sc; v.w *= sc;
    *reinterpret_cast<float4*>(o + (q << 2)) = v;
  }
}

}  // namespace

extern "C" void kernel_launch(void* const* d_in, const int* in_sizes, int n_in,
                              void* d_out, int out_size, void* d_ws, size_t ws_size,
                              hipStream_t stream) {
  (void)in_sizes; (void)n_in; (void)out_size; (void)ws_size;
  const float* x      = (const float*)d_in[0];
  const float* cent   = (const float*)d_in[1];
  const float* conv_w = (const float*)d_in[2];
  const float* conv_b = (const float*)d_in[3];
  float* out = (float*)d_out;
  float* ws  = (float*)d_ws;

  // ws (floats): A 2097152 | wt 32768 | ssqp 16384  = 8.59 MB (proven-safe)
  float* A    = ws;
  float* wt   = A + (size_t)NI * PIXN * KCL;
  float* ssqp = wt + 32768;

  k0_wt     <<<128, 256, 0, stream>>>(conv_w, wt);
  k1a_logits<<<512, 256, 0, stream>>>(x, wt, conv_b, A);
  k2a_vlad  <<<256, 512, 0, stream>>>(x, A, cent, out, ssqp);
  k2c_norm  <<<256, 256, 0, stream>>>(ssqp, out);
}